// Round 1
// baseline (33.488 us; speedup 1.0000x reference)
//
#include <hip/hip_runtime.h>

// Problem: B=4, Q=256, K=256, H=768, D=768, NUM_LEN=100
// s[b,q,k,h] = q[b,q,h] + k[b,k,h] + emb[lm[b,q,k],h]
// attention_scores[b,q,k] = (dot(s,W1)+b1) * attention_mask  -> softmax over K
// scores[b,q,k,c] = softmax_c(dot(s,W2[c])+b2[c])
// content = probs @ m
// Everything decomposes through the linear maps; s is never materialized.

#define Hn 768
#define Bn 4
#define Qn 256
#define Kn 256
#define Dn 768

// ws float layout:
//  qP  [1024][8]  @ 0        (slot 0 = W1 dot, slots 1..5 = W2 dots)
//  kP  [1024][8]  @ 8192
//  eP  [100][8]   @ 16384
//  probs [1024][256] @ 17408
#define WS_KP 8192
#define WS_EP 16384
#define WS_PROBS 17408

__global__ __launch_bounds__(256) void proj_kernel(
    const float* __restrict__ q, const float* __restrict__ k,
    const float* __restrict__ emb, const float* __restrict__ W1,
    const float* __restrict__ W2, float* __restrict__ ws)
{
    int wid  = blockIdx.x * 4 + (threadIdx.x >> 6);   // one wave per row
    int lane = threadIdx.x & 63;
    const float* src;
    float* dst;
    if (wid < 1024)      { src = q + wid * Hn;            dst = ws + wid * 8; }
    else if (wid < 2048) { src = k + (wid - 1024) * Hn;   dst = ws + WS_KP + (wid - 1024) * 8; }
    else {
        int r = wid - 2048;
        if (r >= 100) return;
        src = emb + r * Hn; dst = ws + WS_EP + r * 8;
    }
    float acc[6] = {0.f, 0.f, 0.f, 0.f, 0.f, 0.f};
    #pragma unroll
    for (int i = 0; i < 12; ++i) {
        int h = i * 64 + lane;
        float x = src[h];
        acc[0] = fmaf(x, W1[h], acc[0]);
        #pragma unroll
        for (int c = 0; c < 5; ++c)
            acc[1 + c] = fmaf(x, W2[c * Hn + h], acc[1 + c]);
    }
    #pragma unroll
    for (int j = 0; j < 6; ++j) {
        float v = acc[j];
        #pragma unroll
        for (int off = 32; off > 0; off >>= 1)
            v += __shfl_down(v, off, 64);
        if (lane == 0) dst[j] = v;
    }
}

__global__ __launch_bounds__(256) void score_kernel(
    const float* __restrict__ ws_proj, const float* __restrict__ am,
    const int* __restrict__ lm, const float* __restrict__ b1,
    const float* __restrict__ b2, float* __restrict__ scores_out,
    float* __restrict__ probs_out)
{
    const float* qP = ws_proj;
    const float* kP = ws_proj + WS_KP;
    const float* eP = ws_proj + WS_EP;
    int bq = blockIdx.x;            // b*256 + q
    int b  = bq >> 8;
    int t  = threadIdx.x;           // k index

    float qp[6];
    #pragma unroll
    for (int j = 0; j < 6; ++j) qp[j] = qP[bq * 8 + j];   // uniform -> scalar loads

    int krow = b * Kn + t;
    float4 ka = *(const float4*)&kP[krow * 8];
    float4 kb = *(const float4*)&kP[krow * 8 + 4];
    float kp[6] = {ka.x, ka.y, ka.z, ka.w, kb.x, kb.y};

    int l = lm[(size_t)bq * Kn + t];
    float4 ea = *(const float4*)&eP[l * 8];
    float4 eb = *(const float4*)&eP[l * 8 + 4];
    float ep[6] = {ea.x, ea.y, ea.z, ea.w, eb.x, eb.y};

    float amv = am[(size_t)bq * Kn + t];
    float as  = (qp[0] + kp[0] + ep[0] + b1[0]) * amv;

    // 5-class softmax -> scores output
    float lg[5];
    float mx5 = -1e30f;
    #pragma unroll
    for (int c = 0; c < 5; ++c) {
        lg[c] = qp[c + 1] + kp[c + 1] + ep[c + 1] + b2[c];
        mx5 = fmaxf(mx5, lg[c]);
    }
    float s5 = 0.f;
    #pragma unroll
    for (int c = 0; c < 5; ++c) { lg[c] = __expf(lg[c] - mx5); s5 += lg[c]; }
    float inv5 = 1.f / s5;
    float* so = scores_out + (size_t)(bq * Kn + t) * 5;
    #pragma unroll
    for (int c = 0; c < 5; ++c) so[c] = lg[c] * inv5;

    // softmax over K (block = one (b,q) row, thread = k)
    __shared__ float red[256];
    red[t] = as;
    __syncthreads();
    for (int s = 128; s > 0; s >>= 1) {
        if (t < s) red[t] = fmaxf(red[t], red[t + s]);
        __syncthreads();
    }
    float mx = red[0];
    __syncthreads();
    float e = __expf(as - mx);
    red[t] = e;
    __syncthreads();
    for (int s = 128; s > 0; s >>= 1) {
        if (t < s) red[t] += red[t + s];
        __syncthreads();
    }
    float inv = 1.f / red[0];
    probs_out[(size_t)bq * Kn + t] = e * inv;
}

// content[b,q,d] = sum_k probs[b,q,k] * m[b,k,d]
// grid = B * (Q/8) * 3 ; block 256 ; each thread owns one d column, 8 q rows
__global__ __launch_bounds__(256) void pv_kernel(
    const float* __restrict__ probs, const float* __restrict__ m,
    float* __restrict__ out)
{
    int bid = blockIdx.x;
    int dt = bid % 3;
    int qt = (bid / 3) & 31;
    int b  = bid / 96;
    __shared__ float p[8 * 256];
    int t = threadIdx.x;
    const float* psrc = probs + ((size_t)(b * Qn + qt * 8) * Kn);
    #pragma unroll
    for (int i = 0; i < 8; ++i) p[t + i * 256] = psrc[t + i * 256];
    __syncthreads();

    int d = dt * 256 + t;
    float acc[8] = {0.f, 0.f, 0.f, 0.f, 0.f, 0.f, 0.f, 0.f};
    const float* mb = m + (size_t)b * Kn * Dn + d;
    for (int k0 = 0; k0 < 256; k0 += 4) {
        float mv0 = mb[(size_t)(k0 + 0) * Dn];
        float mv1 = mb[(size_t)(k0 + 1) * Dn];
        float mv2 = mb[(size_t)(k0 + 2) * Dn];
        float mv3 = mb[(size_t)(k0 + 3) * Dn];
        #pragma unroll
        for (int qi = 0; qi < 8; ++qi) {
            float4 pv = *(const float4*)&p[qi * 256 + k0];
            acc[qi] = fmaf(pv.x, mv0, acc[qi]);
            acc[qi] = fmaf(pv.y, mv1, acc[qi]);
            acc[qi] = fmaf(pv.z, mv2, acc[qi]);
            acc[qi] = fmaf(pv.w, mv3, acc[qi]);
        }
    }
    float* ob = out + ((size_t)(b * Qn + qt * 8) * Dn) + d;
    #pragma unroll
    for (int qi = 0; qi < 8; ++qi) ob[qi * Dn] = acc[qi];
}

extern "C" void kernel_launch(void* const* d_in, const int* in_sizes, int n_in,
                              void* d_out, int out_size, void* d_ws, size_t ws_size,
                              hipStream_t stream) {
    const float* q   = (const float*)d_in[0];
    const float* k   = (const float*)d_in[1];
    const float* m   = (const float*)d_in[2];
    const float* am  = (const float*)d_in[3];
    const float* emb = (const float*)d_in[4];
    const float* W1  = (const float*)d_in[5];
    const float* b1  = (const float*)d_in[6];
    const float* W2  = (const float*)d_in[7];
    const float* b2  = (const float*)d_in[8];
    const int*   lm  = (const int*)d_in[9];

    float* out         = (float*)d_out;
    float* out_content = out;                 // [4,256,768]
    float* out_scores  = out + Bn * Qn * Dn;  // [4,256,256,5]

    float* ws    = (float*)d_ws;
    float* probs = ws + WS_PROBS;

    proj_kernel<<<537, 256, 0, stream>>>(q, k, emb, W1, W2, ws);
    score_kernel<<<Bn * Qn, 256, 0, stream>>>(ws, am, lm, b1, b2, out_scores, probs);
    pv_kernel<<<Bn * (Qn / 8) * 3, 256, 0, stream>>>(probs, m, out_content);
}

// Round 2
// 27.327 us; speedup vs baseline: 1.2254x; 1.2254x over previous
//
#include <hip/hip_runtime.h>

// Problem: B=4, Q=256, K=256, H=768, D=768, NUM_LEN=100
// s[b,q,k,h] = q[b,q,h] + k[b,k,h] + emb[lm[b,q,k],h]  (never materialized)
// attention_scores = (dot(s,W1)+b1)*mask -> softmax over K -> probs
// scores = softmax_c(dot(s,W2[c])+b2[c])
// content = probs @ m

#define Hn 768
#define Bn 4
#define Qn 256
#define Kn 256
#define Dn 768

// ws float layout:
//  qP  [1024][8]  @ 0        (slot 0 = W1 dot, slots 1..5 = W2 dots)
//  kP  [1024][8]  @ 8192
//  eP  [100][8]   @ 16384
//  probs [1024][256] @ 17408
#define WS_KP 8192
#define WS_EP 16384
#define WS_PROBS 17408

__global__ __launch_bounds__(256) void proj_kernel(
    const float* __restrict__ q, const float* __restrict__ k,
    const float* __restrict__ emb, const float* __restrict__ W1,
    const float* __restrict__ W2, float* __restrict__ ws)
{
    int wid  = blockIdx.x * 4 + (threadIdx.x >> 6);   // one wave per row
    int lane = threadIdx.x & 63;
    const float* src;
    float* dst;
    if (wid < 1024)      { src = q + wid * Hn;            dst = ws + wid * 8; }
    else if (wid < 2048) { src = k + (wid - 1024) * Hn;   dst = ws + WS_KP + (wid - 1024) * 8; }
    else {
        int r = wid - 2048;
        if (r >= 100) return;
        src = emb + r * Hn; dst = ws + WS_EP + r * 8;
    }
    float acc[6] = {0.f, 0.f, 0.f, 0.f, 0.f, 0.f};
    #pragma unroll
    for (int i = 0; i < 3; ++i) {                 // 3 x (64 lanes x float4) = 768
        int h = i * 256 + lane * 4;
        float4 x  = *(const float4*)&src[h];
        float4 w1 = *(const float4*)&W1[h];
        acc[0] += x.x * w1.x + x.y * w1.y + x.z * w1.z + x.w * w1.w;
        #pragma unroll
        for (int c = 0; c < 5; ++c) {
            float4 w2 = *(const float4*)&W2[c * Hn + h];
            acc[1 + c] += x.x * w2.x + x.y * w2.y + x.z * w2.z + x.w * w2.w;
        }
    }
    #pragma unroll
    for (int j = 0; j < 6; ++j) {
        float v = acc[j];
        #pragma unroll
        for (int off = 32; off > 0; off >>= 1)
            v += __shfl_xor(v, off, 64);
        if (lane == 0) dst[j] = v;
    }
}

__global__ __launch_bounds__(256) void score_kernel(
    const float* __restrict__ ws_proj, const float* __restrict__ am,
    const int* __restrict__ lm, const float* __restrict__ b1,
    const float* __restrict__ b2, float* __restrict__ scores_out,
    float* __restrict__ probs_out)
{
    const float* qP = ws_proj;
    const float* kP = ws_proj + WS_KP;
    const float* eP = ws_proj + WS_EP;
    int bq = blockIdx.x;            // b*256 + q
    int b  = bq >> 8;
    int t  = threadIdx.x;           // k index
    int wave = t >> 6, lane = t & 63;

    float qp[6];
    #pragma unroll
    for (int j = 0; j < 6; ++j) qp[j] = qP[bq * 8 + j];   // uniform -> scalar loads

    int krow = b * Kn + t;
    float4 ka = *(const float4*)&kP[krow * 8];
    float4 kb = *(const float4*)&kP[krow * 8 + 4];
    float kp[6] = {ka.x, ka.y, ka.z, ka.w, kb.x, kb.y};

    int l = lm[(size_t)bq * Kn + t];
    float4 ea = *(const float4*)&eP[l * 8];
    float4 eb = *(const float4*)&eP[l * 8 + 4];
    float ep[6] = {ea.x, ea.y, ea.z, ea.w, eb.x, eb.y};

    float amv = am[(size_t)bq * Kn + t];
    float as  = (qp[0] + kp[0] + ep[0] + b1[0]) * amv;

    // ---- 5-class softmax -> LDS staging -> vectorized store ----
    __shared__ float sc[Kn * 5];     // 5 KB
    float lg[5];
    float mx5 = -1e30f;
    #pragma unroll
    for (int c = 0; c < 5; ++c) {
        lg[c] = qp[c + 1] + kp[c + 1] + ep[c + 1] + b2[c];
        mx5 = fmaxf(mx5, lg[c]);
    }
    float s5 = 0.f;
    #pragma unroll
    for (int c = 0; c < 5; ++c) { lg[c] = __expf(lg[c] - mx5); s5 += lg[c]; }
    float inv5 = 1.f / s5;
    #pragma unroll
    for (int c = 0; c < 5; ++c) sc[t * 5 + c] = lg[c] * inv5;

    // ---- softmax over K: wave shfl reduce + tiny LDS combine ----
    __shared__ float wmaxA[4], wsumA[4];
    float wm = as;
    #pragma unroll
    for (int off = 32; off > 0; off >>= 1) wm = fmaxf(wm, __shfl_xor(wm, off, 64));
    if (lane == 0) wmaxA[wave] = wm;
    __syncthreads();
    float mx = fmaxf(fmaxf(wmaxA[0], wmaxA[1]), fmaxf(wmaxA[2], wmaxA[3]));
    float e = __expf(as - mx);
    float wsum = e;
    #pragma unroll
    for (int off = 32; off > 0; off >>= 1) wsum += __shfl_xor(wsum, off, 64);
    if (lane == 0) wsumA[wave] = wsum;
    __syncthreads();
    float inv = 1.f / (wsumA[0] + wsumA[1] + wsumA[2] + wsumA[3]);
    probs_out[(size_t)bq * Kn + t] = e * inv;

    // vectorized scores store: 1280 floats = 320 float4
    float4* so4 = (float4*)(scores_out + (size_t)bq * Kn * 5);
    const float4* sc4 = (const float4*)sc;
    so4[t] = sc4[t];
    if (t < 64) so4[256 + t] = sc4[256 + t];
}

// content[b,q,d] = sum_k probs[b,q,k] * m[b,k,d]
// grid = B(4) x qt(32: 8 q rows) x dt(6: 128 d cols) = 768 blocks, 256 thr
// thread: kh = t>>7 (k half), c = t&127 (d col)
__global__ __launch_bounds__(256) void pv_kernel(
    const float* __restrict__ probs, const float* __restrict__ m,
    float* __restrict__ out)
{
    int bid = blockIdx.x;
    int dt = bid % 6;
    int qt = (bid / 6) & 31;
    int b  = bid / 192;
    __shared__ float p[8][Kn];       // 8 KB
    __shared__ float part[8][128];   // 4 KB
    int t = threadIdx.x;
    int kh = t >> 7;
    int c  = t & 127;
    int d  = dt * 128 + c;

    const float* psrc = probs + ((size_t)(b * Qn + qt * 8) * Kn);
    #pragma unroll
    for (int i = 0; i < 8; ++i) p[i][t] = psrc[t + i * Kn];
    __syncthreads();

    float acc[8] = {0.f, 0.f, 0.f, 0.f, 0.f, 0.f, 0.f, 0.f};
    const float* mb = m + (size_t)b * Kn * Dn + d;
    int k0 = kh * 128;
    for (int k = k0; k < k0 + 128; k += 4) {
        float mv0 = mb[(size_t)(k + 0) * Dn];
        float mv1 = mb[(size_t)(k + 1) * Dn];
        float mv2 = mb[(size_t)(k + 2) * Dn];
        float mv3 = mb[(size_t)(k + 3) * Dn];
        #pragma unroll
        for (int qi = 0; qi < 8; ++qi) {
            float4 pv = *(const float4*)&p[qi][k];
            acc[qi] = fmaf(pv.x, mv0, acc[qi]);
            acc[qi] = fmaf(pv.y, mv1, acc[qi]);
            acc[qi] = fmaf(pv.z, mv2, acc[qi]);
            acc[qi] = fmaf(pv.w, mv3, acc[qi]);
        }
    }
    if (kh == 1) {
        #pragma unroll
        for (int qi = 0; qi < 8; ++qi) part[qi][c] = acc[qi];
    }
    __syncthreads();
    if (kh == 0) {
        float* ob = out + ((size_t)(b * Qn + qt * 8) * Dn) + d;
        #pragma unroll
        for (int qi = 0; qi < 8; ++qi) ob[qi * Dn] = acc[qi] + part[qi][c];
    }
}

extern "C" void kernel_launch(void* const* d_in, const int* in_sizes, int n_in,
                              void* d_out, int out_size, void* d_ws, size_t ws_size,
                              hipStream_t stream) {
    const float* q   = (const float*)d_in[0];
    const float* k   = (const float*)d_in[1];
    const float* m   = (const float*)d_in[2];
    const float* am  = (const float*)d_in[3];
    const float* emb = (const float*)d_in[4];
    const float* W1  = (const float*)d_in[5];
    const float* b1  = (const float*)d_in[6];
    const float* W2  = (const float*)d_in[7];
    const float* b2  = (const float*)d_in[8];
    const int*   lm  = (const int*)d_in[9];

    float* out         = (float*)d_out;
    float* out_content = out;                 // [4,256,768]
    float* out_scores  = out + Bn * Qn * Dn;  // [4,256,256,5]

    float* ws    = (float*)d_ws;
    float* probs = ws + WS_PROBS;

    proj_kernel<<<537, 256, 0, stream>>>(q, k, emb, W1, W2, ws);
    score_kernel<<<Bn * Qn, 256, 0, stream>>>(ws, am, lm, b1, b2, out_scores, probs);
    pv_kernel<<<Bn * (Qn / 8) * 6, 256, 0, stream>>>(probs, m, out_content);
}